// Round 13
// baseline (35.647 us; speedup 1.0000x reference)
//
#include <hip/hip_runtime.h>

// GaussianAntecedent: out[n,r] = mem[n,r] / (sum_r mem[n,r] + 1e-8)
// mem = exp2( sum_d ( acc += max( negqq_rd*(x-c)^2, L ) ) )
//   negqq = -0.5*log2(e)/(sigma+eps)^2 ,  L = log2(1e-8) < 0
//
// R12 post-mortem: design C put the constant broadcast on the per-CU LDS
// pipe (16 uniform ds_read_b128/rule x 16 resident waves ~ 12us of
// serialized LDS service) -- LDS pipe was the bottleneck, not VALU.
// R13 design D: constants go through the SCALAR pipe into SGPRs:
//  - lane = row: own x[32] in VGPRs (one coalesced load, pinned)
//  - wave w handles rules 16w..16w+15 (6250 waves, 6.1/SIMD demand)
//  - per-rule c/negqq table read as wave-uniform s_loads (readfirstlane
//    forces scalar path); 16-rule loop fully unrolled so s_loads pipeline
//    >=1 rule ahead of the ~174cy/rule VALU stream
//  - inner math: z=x-c (1 sgpr), zz=z*z, u=fma(zz,negqq,acc) (1 sgpr),
//    cl=acc+L2 (inline), acc=max(u,cl)  -- <=1 SGPR per VALU op
//  - LDS only for mem tile [rule][row] + partial sums: 18.7KB, 8 blk/CU

typedef float v2f __attribute__((ext_vector_type(2)));

constexpr int DDIM = 32;
constexpr int RR   = 64;
constexpr int ROWS = 64;   // rows per block
constexpr int MP   = 68;   // mem tile pitch (floats)
constexpr int PP   = 5;    // partials pitch (floats)

__device__ inline float fast_exp2(float x) {
#if __has_builtin(__builtin_amdgcn_exp2f)
    return __builtin_amdgcn_exp2f(x);
#else
    return exp2f(x);
#endif
}

// ---- setup: per-rule table [ c[0..31] | negqq[0..31] ] (64 floats/rule) ----
__global__ void gauss_setup_kernel(const float* __restrict__ centers,
                                   const float* __restrict__ sigma,
                                   float* __restrict__ ws) {
    const float KQ = 0.72134752044448170f;   // 0.5 * log2(e)
    int idx = blockIdx.x * blockDim.x + threadIdx.x;
    if (idx < RR * 64) {
        int r = idx >> 6, k = idx & 63, d = k & 31;
        if (k < DDIM) {
            ws[idx] = centers[r * DDIM + d];
        } else {
            float s = sigma[r * DDIM + d] + 1e-8f;
            ws[idx] = -KQ / (s * s);
        }
    }
}

__global__ __launch_bounds__(256, 4) void gauss_main(
    const float* __restrict__ X,
    const float* __restrict__ tab,    // d_ws: 64 rules x [c[32]|negqq[32]]
    float* __restrict__ out, int N)
{
    __shared__ float memL[RR * MP];       // 17.4 KB  [rule][row]
    __shared__ float partL[ROWS * PP];    // 1.3 KB   [row][wave]

    const int tid  = threadIdx.x;
    const int lane = tid & 63;
    // wave index, forced wave-uniform so table reads take the scalar path
    const int w    = __builtin_amdgcn_readfirstlane(tid >> 6);
    const int n0   = blockIdx.x * ROWS;

    // ---- own row -> VGPRs (per-lane coalesced, one vmcnt wait) ----
    const int n  = n0 + lane;
    const int nn = (n < N) ? n : (N - 1);   // clamp; stores predicated
    const float4* __restrict__ xr =
        reinterpret_cast<const float4*>(X + (size_t)nn * DDIM);
    v2f x2[16];
    #pragma unroll
    for (int j = 0; j < 8; ++j) {
        float4 v = xr[j];
        x2[2 * j]     = (v2f){v.x, v.y};
        x2[2 * j + 1] = (v2f){v.z, v.w};
    }
    #pragma unroll
    for (int j = 0; j < 16; ++j) asm volatile("" : "+v"(x2[j]));

    const float LC = -26.575424759098897f;   // log2(1e-8)
    const v2f L2 = {LC, LC};
    float S = 0.f;

    // ---- 16 rules for this wave; fully unrolled; constants via s_load ----
    #pragma unroll
    for (int rr = 0; rr < 16; ++rr) {
        const int r = w * 16 + rr;   // wave-uniform
        const v2f* __restrict__ cr =
            reinterpret_cast<const v2f*>(tab + r * 64);   // c pairs
        const v2f* __restrict__ qr = cr + DDIM / 2;       // negqq pairs

        v2f acc[4] = {{0.f,0.f},{0.f,0.f},{0.f,0.f},{0.f,0.f}};
        #pragma unroll
        for (int p = 0; p < 16; ++p) {
            v2f z  = x2[p] - cr[p];                                   // 1 sgpr
            v2f zz = z * z;
            v2f u  = __builtin_elementwise_fma(zz, qr[p], acc[p & 3]); // 1 sgpr
            v2f cl = acc[p & 3] + L2;                                  // inline
            acc[p & 3] = __builtin_elementwise_max(u, cl);
        }
        v2f a = (acc[0] + acc[1]) + (acc[2] + acc[3]);
        float mem = fast_exp2(a.x + a.y);
        S += mem;
        memL[r * MP + lane] = mem;    // stride-1 across lanes: conflict-free
    }
    partL[lane * PP + w] = S;         // (5*lane+w)%32: 2-way, free

    __syncthreads();   // mem tile + partials ready

    // ---- epilogue: normalize + coalesced float4 stores ----
    const int i  = tid >> 2;          // row 0..63
    const int qd = tid & 3;           // rule-quad selector
    float Ssum = partL[i * PP + 0] + partL[i * PP + 1] +
                 partL[i * PP + 2] + partL[i * PP + 3];
    float rs = __builtin_amdgcn_rcpf(Ssum + 1e-8f);
    if (n0 + i < N) {
        #pragma unroll
        for (int t = 0; t < 4; ++t) {
            const int r4 = t * 16 + qd * 4;
            float4 o;
            o.x = memL[(r4 + 0) * MP + i] * rs;
            o.y = memL[(r4 + 1) * MP + i] * rs;
            o.z = memL[(r4 + 2) * MP + i] * rs;
            o.w = memL[(r4 + 3) * MP + i] * rs;
            *reinterpret_cast<float4*>(&out[(size_t)(n0 + i) * RR + r4]) = o;
        }
    }
}

extern "C" void kernel_launch(void* const* d_in, const int* in_sizes, int n_in,
                              void* d_out, int out_size, void* d_ws, size_t ws_size,
                              hipStream_t stream) {
    const float* X       = (const float*)d_in[0];
    const float* centers = (const float*)d_in[1];
    const float* sigma   = (const float*)d_in[2];
    float* out = (float*)d_out;
    float* ws  = (float*)d_ws;   // needs 64*64*4 = 16 KB

    const int N = in_sizes[0] / DDIM;  // 100000

    // 1) build per-rule c/negqq table (4096 floats)
    gauss_setup_kernel<<<16, 256, 0, stream>>>(centers, sigma, ws);

    // 2) main: 1563 blocks x 256 threads (64 rows/block, rules split 4 ways)
    const int grid = (N + ROWS - 1) / ROWS;
    gauss_main<<<grid, 256, 0, stream>>>(X, ws, out, N);
}

// Round 14
// 32.902 us; speedup vs baseline: 1.0834x; 1.0834x over previous
//
#include <hip/hip_runtime.h>

// GaussianAntecedent: out[n,r] = mem[n,r] / (sum_r mem[n,r] + 1e-8)
// mem = exp2( sum_d max( -(q*x + pn)^2 , L ) ),
//   q = sqrt(0.5*log2 e)/(sigma+eps), pn = -c*q, L = log2(1e-8) < 0
//
// R13 post-mortem: four distinct transport designs all land 35-36us; no
// pipe is saturated -- the basin is per-wave exposed latency + fixed
// overhead (2 dispatches, staging serial in every short wave).
// R14 design C2 (one dispatch, max amortization):
//  - setup folded in: each block computes the 4KB q/pn table itself
//    (8 divides/thread, once per block, hidden under X loads)
//  - ROWS=128/block: lane owns TWO rows (n0+lane, n0+64+lane); each
//    uniform ds_read_b128 of constants feeds 8 packed ops (2 independent
//    row chains = 2x ILP, constant transport per row halved)
//  - mem tile [rule][row] pitch 130 (write conflict-free, read 2-way),
//    contiguous-4KB epilogue stores, per-lane S (no cross-lane reduce)
//  - 782 blocks x 256 thr; 52.7KB LDS -> 3 blocks/CU

typedef float v2f __attribute__((ext_vector_type(2)));

constexpr int DDIM = 32;
constexpr int RR   = 64;
constexpr int ROWS = 128;         // rows per block (2 per lane)
constexpr int MP   = 130;         // mem tile pitch (floats)
constexpr int PP   = 5;           // partials pitch

__device__ inline float fast_exp2(float x) {
#if __has_builtin(__builtin_amdgcn_exp2f)
    return __builtin_amdgcn_exp2f(x);
#else
    return exp2f(x);
#endif
}

__global__ __launch_bounds__(256, 2) void gauss_main(
    const float* __restrict__ X,
    const float* __restrict__ centers,
    const float* __restrict__ sigma,
    float* __restrict__ out, int N)
{
    __shared__ float tabL[RR * 64];       // 16 KB  [rule]{q[32]|pn[32]}
    __shared__ float memL[RR * MP];       // 33.3 KB [rule][row]
    __shared__ float partL[ROWS * PP];    // 2.56 KB [row][wave]
    __shared__ float rsL[ROWS];           // 0.5 KB  rcp(S) per row

    const int tid  = threadIdx.x;
    const int lane = tid & 63;
    const int w    = tid >> 6;
    const int n0   = blockIdx.x * ROWS;

    // ---- own rows -> VGPRs (issued first; latency hides table build) ----
    const int na = n0 + lane;
    const int nb = n0 + 64 + lane;
    const int ca = (na < N) ? na : (N - 1);
    const int cb = (nb < N) ? nb : (N - 1);
    const float4* __restrict__ xra =
        reinterpret_cast<const float4*>(X + (size_t)ca * DDIM);
    const float4* __restrict__ xrb =
        reinterpret_cast<const float4*>(X + (size_t)cb * DDIM);
    v2f xa2[16], xb2[16];
    #pragma unroll
    for (int j = 0; j < 8; ++j) {
        float4 va = xra[j], vb = xrb[j];
        xa2[2 * j]     = (v2f){va.x, va.y};
        xa2[2 * j + 1] = (v2f){va.z, va.w};
        xb2[2 * j]     = (v2f){vb.x, vb.y};
        xb2[2 * j + 1] = (v2f){vb.z, vb.w};
    }

    // ---- build q/pn table in LDS (once per block; 8 divides/thread) ----
    const float SQK = 0.84932180028801907f;   // sqrt(0.5 * log2(e))
    #pragma unroll
    for (int i = 0; i < 8; ++i) {
        const int pi = tid * 8 + i;           // (rule, dim) pair 0..2047
        const int r  = pi >> 5, d = pi & 31;
        float q  = SQK / (sigma[r * DDIM + d] + 1e-8f);
        tabL[r * 64 + d]        = q;
        tabL[r * 64 + DDIM + d] = -centers[r * DDIM + d] * q;
    }

    #pragma unroll
    for (int j = 0; j < 16; ++j) asm volatile("" : "+v"(xa2[j]), "+v"(xb2[j]));

    __syncthreads();   // table ready

    const float LC = -26.575424759098897f;   // log2(1e-8)
    const v2f L2 = {LC, LC};
    float Sa = 0.f, Sb = 0.f;

    // ---- 16 rules for this wave; both rows per constant read ----
    #pragma unroll
    for (int rr = 0; rr < 16; ++rr) {
        const int r = w * 16 + rr;
        const float4* __restrict__ tp =
            reinterpret_cast<const float4*>(&tabL[r * 64]);

        v2f Aa[2] = {{0.f,0.f},{0.f,0.f}};
        v2f Ab[2] = {{0.f,0.f},{0.f,0.f}};
        #pragma unroll
        for (int j = 0; j < 8; ++j) {
            float4 qf = tp[j];        // q  dims 4j..4j+3 (uniform broadcast)
            float4 pf = tp[8 + j];    // pn dims 4j..4j+3
            v2f q0 = {qf.x, qf.y}, q1 = {qf.z, qf.w};
            v2f p0 = {pf.x, pf.y}, p1 = {pf.z, pf.w};
            v2f ta0 = __builtin_elementwise_fma(q0, xa2[2*j],   p0);
            v2f ta1 = __builtin_elementwise_fma(q1, xa2[2*j+1], p1);
            v2f tb0 = __builtin_elementwise_fma(q0, xb2[2*j],   p0);
            v2f tb1 = __builtin_elementwise_fma(q1, xb2[2*j+1], p1);
            // B = max(B - t*t, B + L)
            v2f ua0 = __builtin_elementwise_fma(ta0, -ta0, Aa[0]);
            v2f ua1 = __builtin_elementwise_fma(ta1, -ta1, Aa[1]);
            v2f ub0 = __builtin_elementwise_fma(tb0, -tb0, Ab[0]);
            v2f ub1 = __builtin_elementwise_fma(tb1, -tb1, Ab[1]);
            Aa[0] = __builtin_elementwise_max(ua0, Aa[0] + L2);
            Aa[1] = __builtin_elementwise_max(ua1, Aa[1] + L2);
            Ab[0] = __builtin_elementwise_max(ub0, Ab[0] + L2);
            Ab[1] = __builtin_elementwise_max(ub1, Ab[1] + L2);
        }
        v2f aa = Aa[0] + Aa[1];
        v2f ab = Ab[0] + Ab[1];
        float ma = fast_exp2(aa.x + aa.y);
        float mb = fast_exp2(ab.x + ab.y);
        Sa += ma;
        Sb += mb;
        memL[r * MP + lane]      = ma;   // stride-1 across lanes: clean
        memL[r * MP + 64 + lane] = mb;
    }
    partL[lane * PP + w]        = Sa;    // (5*lane+w)%32: 2-way, free
    partL[(64 + lane) * PP + w] = Sb;

    __syncthreads();   // mem tile + partials ready

    if (tid < ROWS) {
        float s = partL[tid * PP + 0] + partL[tid * PP + 1] +
                  partL[tid * PP + 2] + partL[tid * PP + 3];
        rsL[tid] = __builtin_amdgcn_rcpf(s + 1e-8f);
    }
    __syncthreads();   // rs ready

    // ---- epilogue: contiguous 4KB-per-step float4 stores ----
    // flat float4 index within the block tile: ch*256 + tid
    const int nvalid = N - n0;   // rows in this block (128 except last)
    #pragma unroll
    for (int ch = 0; ch < 8; ++ch) {
        const int f4  = ch * 256 + tid;       // 0..2047
        const int row = f4 >> 4;              // 0..127
        const int r4  = (f4 & 15) * 4;        // rule quad base
        if (row < nvalid) {
            float rs = rsL[row];
            float4 o;
            o.x = memL[(r4 + 0) * MP + row] * rs;
            o.y = memL[(r4 + 1) * MP + row] * rs;
            o.z = memL[(r4 + 2) * MP + row] * rs;
            o.w = memL[(r4 + 3) * MP + row] * rs;
            *reinterpret_cast<float4*>(&out[(size_t)(n0 + row) * RR + r4]) = o;
        }
    }
}

extern "C" void kernel_launch(void* const* d_in, const int* in_sizes, int n_in,
                              void* d_out, int out_size, void* d_ws, size_t ws_size,
                              hipStream_t stream) {
    const float* X       = (const float*)d_in[0];
    const float* centers = (const float*)d_in[1];
    const float* sigma   = (const float*)d_in[2];
    float* out = (float*)d_out;

    const int N = in_sizes[0] / DDIM;  // 100000
    const int grid = (N + ROWS - 1) / ROWS;   // 782
    gauss_main<<<grid, 256, 0, stream>>>(X, centers, sigma, out, N);
}